// Round 13
// baseline (220.390 us; speedup 1.0000x reference)
//
#include <hip/hip_runtime.h>
#include <cstddef>
#include <cstdint>

#define CCH 256   // channels
#define DQK 32    // q/k channels
#define NPX 4096  // H*W
#define BQ2 128   // queries per block (8 waves x 16-query strips)
#define BM  64    // key tile per iteration
#define NB  4     // batch

typedef __attribute__((ext_vector_type(8))) short bf16x8;   // 8 bf16 = 4 VGPR (MFMA A/B frag)
typedef __attribute__((ext_vector_type(4))) float f32x4;    // MFMA C/D frag
typedef __attribute__((ext_vector_type(4))) unsigned int u32x4;

__device__ inline unsigned short f2bf(float f) {            // RNE float->bf16
    unsigned u = __builtin_bit_cast(unsigned, f);
    u += 0x7FFFu + ((u >> 16) & 1u);
    return (unsigned short)(u >> 16);
}
__device__ inline float bf2f(unsigned short h) {
    unsigned u = (unsigned)h << 16;
    return __builtin_bit_cast(float, u);
}

// ---------------------------------------------------------------------------
// Fused q/k/v 1x1-conv projection -> bf16 outputs in ws (unchanged R10).
//   qT: [NB][NPX][32], kT: [NB][NPX][32], v: [NB][CCH][NPX]
// 1 px/thread, 1280 blocks (64 slabs x 20 oc-groups), slab pinned to XCD.
// ---------------------------------------------------------------------------
__global__ __launch_bounds__(256) void proj_kernel(
    const float* __restrict__ x,
    const float* __restrict__ Wq, const float* __restrict__ bq,
    const float* __restrict__ Wk, const float* __restrict__ bk,
    const float* __restrict__ Wv, const float* __restrict__ bv,
    unsigned short* __restrict__ ws)
{
    const int tid  = threadIdx.x;
    const int bid  = blockIdx.x;
    const int xcd  = bid & 7;
    const int rem  = bid >> 3;           // 0..159
    const int sidx = rem / 20;           // slab index within XCD 0..7
    const int ocg  = rem % 20;           // oc-group 0..19
    const int slab = xcd + 8 * sidx;     // 0..63
    const int b    = slab >> 4;          // batch
    const int px   = slab & 15;          // pixel slab in batch
    const int o0   = ocg * 16;
    const int n    = px * 256 + tid;     // this thread's pixel

    const float* Wbase;
    const float* bbase;
    if (o0 < 32)      { Wbase = Wq + o0 * CCH;        bbase = bq + o0; }
    else if (o0 < 64) { Wbase = Wk + (o0 - 32) * CCH; bbase = bk + (o0 - 32); }
    else              { Wbase = Wv + (o0 - 64) * CCH; bbase = bv + (o0 - 64); }

    float acc[16];
#pragma unroll
    for (int ol = 0; ol < 16; ++ol) acc[ol] = bbase[ol];

    const float* xp = x + ((size_t)b * CCH) * NPX + n;
#pragma unroll 4
    for (int c = 0; c < CCH; ++c) {
        const float xv = xp[(size_t)c * NPX];
#pragma unroll
        for (int ol = 0; ol < 16; ++ol)
            acc[ol] += Wbase[ol * CCH + c] * xv;
    }

    if (o0 < 64) {
        unsigned short* dstT = ws + ((o0 < 32) ? (size_t)0 : (size_t)NB * NPX * 32);
        const int col0 = o0 & 16;
        unsigned u[8];
#pragma unroll
        for (int h = 0; h < 8; ++h)
            u[h] = (unsigned)f2bf(acc[2 * h]) | ((unsigned)f2bf(acc[2 * h + 1]) << 16);
        u32x4* dp = (u32x4*)(dstT + ((size_t)b * NPX + n) * 32 + col0);
        dp[0] = (u32x4){u[0], u[1], u[2], u[3]};
        dp[1] = (u32x4){u[4], u[5], u[6], u[7]};
    } else {
        unsigned short* vbase = ws + (size_t)2 * NB * NPX * 32;
        const int c0 = o0 - 64;
#pragma unroll
        for (int ol = 0; ol < 16; ++ol)
            vbase[((size_t)(b * CCH + c0 + ol)) * NPX + n] = f2bf(acc[ol]);
    }
}

// ---------------------------------------------------------------------------
// Flash attention, BQ2=128 q/block, 8 waves, double-buffered P, 1 barrier/
// iter, defer-max. R13: K and V REGISTER PREFETCH pipeline -- K(t+1) issued
// right after E(t) consumes kreg (covered by softmax+barrier+PV), V(t+1)
// issued right after PV(t) consumes vpre (covered by E+softmax+barrier).
// ---------------------------------------------------------------------------
__global__ __launch_bounds__(512, 4) void attn_kernel(
    const unsigned short* __restrict__ qT, const unsigned short* __restrict__ kT,
    const unsigned short* __restrict__ vB, const float* __restrict__ x,
    const float* __restrict__ gamma, float* __restrict__ out,
    unsigned short* __restrict__ opart, float* __restrict__ mlm,
    float* __restrict__ mll, int ns)
{
    __shared__ __align__(16) unsigned short Pl[2][BQ2 * 64];  // 32KB, XOR swz
    __shared__ float scb[2][BQ2];
    __shared__ int   flg[2][8];
    __shared__ float l_lds[BQ2];

    const int tid  = threadIdx.x;
    const int lane = tid & 63;
    const int w    = tid >> 6;       // wave 0..7
    const int ln   = lane & 15;
    const int g    = lane >> 4;      // 16-lane group 0..3
    const int bid  = blockIdx.x;

    const int b    = (bid & 7) >> 1;                        // batch -> XCD pair
    const int jb   = ((bid >> 3) << 1) | (bid & 1);         // job in batch
    const int tile = jb / ns;
    const int s    = jb - tile * ns;
    const int n0   = tile * BQ2;

    // softmax query owned by this lane: q = n0 + w*16 + ln
    const bf16x8 qf = *(const bf16x8*)(qT + ((size_t)b * NPX + n0 + w * 16 + ln) * 32 + g * 8);

    f32x4 acc[8][2];
#pragma unroll
    for (int qt = 0; qt < 8; ++qt) {
        acc[qt][0] = (f32x4){0.f, 0.f, 0.f, 0.f};
        acc[qt][1] = (f32x4){0.f, 0.f, 0.f, 0.f};
    }
    float mreg = -INFINITY, lreg = 0.f;

    const unsigned short* kTb = kT + (size_t)b * NPX * 32;
    const unsigned short* vb  = vB + ((size_t)b * CCH + w * 32) * NPX;
    const int kbase = s * (NPX / ns);
    const int iters = NPX / (ns * BM);
    const unsigned swz   = ((unsigned)ln & 7u) << 4;
    const unsigned myrow = (unsigned)(w * 16 + ln) * 128u;

    // ---- register prefetch pipeline: K/V of tile 0
    bf16x8 kreg[4];
    bf16x8 vpre[2][2];
#pragma unroll
    for (int s4 = 0; s4 < 4; ++s4)
        kreg[s4] = *(const bf16x8*)(kTb + (size_t)(kbase + s4 * 16 + ln) * 32 + g * 8);
#pragma unroll
    for (int ct = 0; ct < 2; ++ct) {
        const unsigned short* vrow = vb + (size_t)(ct * 16 + ln) * NPX + kbase + g * 8;
        vpre[ct][0] = *(const bf16x8*)(vrow);
        vpre[ct][1] = *(const bf16x8*)(vrow + 32);
    }

    for (int t = 0; t < iters; ++t) {
        const int mnext = kbase + ((t + 1 < iters) ? (t + 1) : t) * BM;

        // ---- E(t): 4 MFMA from prefetched kreg
        f32x4 e[4];
#pragma unroll
        for (int s4 = 0; s4 < 4; ++s4)
            e[s4] = __builtin_amdgcn_mfma_f32_16x16x32_bf16(
                        kreg[s4], qf, (f32x4){0.f, 0.f, 0.f, 0.f}, 0, 0, 0);
        // ---- issue K(t+1) now; latency covered by softmax+barrier+PV
#pragma unroll
        for (int s4 = 0; s4 < 4; ++s4)
            kreg[s4] = *(const bf16x8*)(kTb + (size_t)(mnext + s4 * 16 + ln) * 32 + g * 8);

        // ---- in-register online softmax with defer-max (THR=8)
        float lm = -INFINITY;
#pragma unroll
        for (int s4 = 0; s4 < 4; ++s4)
#pragma unroll
            for (int rr = 0; rr < 4; ++rr) lm = fmaxf(lm, e[s4][rr]);
        lm = fmaxf(lm, __shfl_xor(lm, 16));
        lm = fmaxf(lm, __shfl_xor(lm, 32));
        const float mnew = (lm <= mreg + 8.0f) ? mreg : lm;  // -inf+8=-inf -> first iter updates
        const float sc   = __expf(mreg - mnew);              // ==1.0 exactly when deferred
        float ps = 0.f;
#pragma unroll
        for (int s4 = 0; s4 < 4; ++s4)
#pragma unroll
            for (int rr = 0; rr < 4; ++rr) {
                const float p = __expf(e[s4][rr] - mnew);
                e[s4][rr] = p;
                ps += p;
            }
        ps += __shfl_xor(ps, 16);
        ps += __shfl_xor(ps, 32);
        lreg = lreg * sc + ps;
        mreg = mnew;

        // ---- P (bf16) -> buf t&1, XOR-swizzled; sc + wave skip-flag
        const int bw = t & 1;
        char* const pwb = (char*)&Pl[bw][0];
#pragma unroll
        for (int s4 = 0; s4 < 4; ++s4) {
            uint2 pk;
            pk.x = (unsigned)f2bf(e[s4][0]) | ((unsigned)f2bf(e[s4][1]) << 16);
            pk.y = (unsigned)f2bf(e[s4][2]) | ((unsigned)f2bf(e[s4][3]) << 16);
            *(uint2*)(pwb + myrow + (((unsigned)(s4 * 32 + g * 8)) ^ swz)) = pk;
        }
        if (g == 0) scb[bw][w * 16 + ln] = sc;
        const int allsk = __all(sc == 1.0f);
        if (lane == 0) flg[bw][w] = allsk;
        __syncthreads();   // the ONLY barrier per iteration

        // ---- PV(t): rescale (unless all sc==1), then 32 MFMA from vpre
        int sk = flg[bw][0];
#pragma unroll
        for (int i = 1; i < 8; ++i) sk &= flg[bw][i];
        if (!sk) {
#pragma unroll
            for (int qt = 0; qt < 8; ++qt) {
                const float scq = scb[bw][qt * 16 + ln];
#pragma unroll
                for (int rr = 0; rr < 4; ++rr) {
                    acc[qt][0][rr] *= scq;
                    acc[qt][1][rr] *= scq;
                }
            }
        }
#pragma unroll
        for (int qt = 0; qt < 8; ++qt) {
            const unsigned rb = (unsigned)(qt * 16 + ln) * 128u;
            const bf16x8 pf0 = *(const bf16x8*)(pwb + rb + (((unsigned)(g * 16))      ^ swz));
            const bf16x8 pf1 = *(const bf16x8*)(pwb + rb + (((unsigned)(64 + g * 16)) ^ swz));
            acc[qt][0] = __builtin_amdgcn_mfma_f32_16x16x32_bf16(vpre[0][0], pf0, acc[qt][0], 0, 0, 0);
            acc[qt][0] = __builtin_amdgcn_mfma_f32_16x16x32_bf16(vpre[0][1], pf1, acc[qt][0], 0, 0, 0);
            acc[qt][1] = __builtin_amdgcn_mfma_f32_16x16x32_bf16(vpre[1][0], pf0, acc[qt][1], 0, 0, 0);
            acc[qt][1] = __builtin_amdgcn_mfma_f32_16x16x32_bf16(vpre[1][1], pf1, acc[qt][1], 0, 0, 0);
        }
        // ---- issue V(t+1) now; latency covered by E(t+1)+softmax+barrier
#pragma unroll
        for (int ct = 0; ct < 2; ++ct) {
            const unsigned short* vrow = vb + (size_t)(ct * 16 + ln) * NPX + mnext + g * 8;
            vpre[ct][0] = *(const bf16x8*)(vrow);
            vpre[ct][1] = *(const bf16x8*)(vrow + 32);
        }
    }

    if (opart) {
        // partial epilogue: raw acc (bf16) + per-query m,l (owner wave writes)
        const size_t sb = (size_t)(s * NB + b);
#pragma unroll
        for (int qt = 0; qt < 8; ++qt)
#pragma unroll
            for (int ct = 0; ct < 2; ++ct) {
                const size_t c0 = sb * CCH + w * 32 + ct * 16 + g * 4;
#pragma unroll
                for (int rr = 0; rr < 4; ++rr)
                    opart[(c0 + rr) * NPX + n0 + qt * 16 + ln] = f2bf(acc[qt][ct][rr]);
            }
        if (g == 0) {
            mlm[sb * NPX + n0 + w * 16 + ln] = mreg;
            mll[sb * NPX + n0 + w * 16 + ln] = lreg;
        }
    } else {
        // direct epilogue (ns==1): need per-query l for ALL queries -> LDS
        if (g == 0) l_lds[w * 16 + ln] = lreg;
        __syncthreads();
        const float gm = gamma[0];
#pragma unroll
        for (int qt = 0; qt < 8; ++qt) {
            const float iv = 1.f / l_lds[qt * 16 + ln];
#pragma unroll
            for (int ct = 0; ct < 2; ++ct) {
                const size_t c0 = (size_t)b * CCH + w * 32 + ct * 16 + g * 4;
#pragma unroll
                for (int rr = 0; rr < 4; ++rr) {
                    const size_t idx = (c0 + rr) * NPX + n0 + qt * 16 + ln;
                    out[idx] = gm * acc[qt][ct][rr] * iv + x[idx];
                }
            }
        }
    }
}

// ---------------------------------------------------------------------------
// Combine: log-sum-exp merge of ns key-slice partials + gamma/residual.
// ---------------------------------------------------------------------------
__global__ __launch_bounds__(256) void combine_kernel(
    const unsigned short* __restrict__ opart,
    const float* __restrict__ mlm, const float* __restrict__ mll,
    const float* __restrict__ x, const float* __restrict__ gamma,
    float* __restrict__ out, int ns)
{
    const int idx = blockIdx.x * 256 + threadIdx.x;   // NB*CCH*512 threads
    const int bc  = idx >> 9;                          // b*CCH + c
    const int b   = bc / CCH;
    const int c   = bc - b * CCH;
    const int n0  = (idx & 511) * 8;

    float M[8];
#pragma unroll
    for (int i = 0; i < 8; ++i) M[i] = -INFINITY;
    for (int s = 0; s < ns; ++s) {
        const float* mp = mlm + ((size_t)(s * NB + b)) * NPX + n0;
#pragma unroll
        for (int i = 0; i < 8; ++i) M[i] = fmaxf(M[i], mp[i]);
    }

    float L[8], O[8];
#pragma unroll
    for (int i = 0; i < 8; ++i) { L[i] = 0.f; O[i] = 0.f; }
    for (int s = 0; s < ns; ++s) {
        const size_t sb = (size_t)(s * NB + b);
        const float* mp = mlm + sb * NPX + n0;
        const float* lp = mll + sb * NPX + n0;
        const bf16x8 v8 = *(const bf16x8*)(opart + (sb * CCH + c) * NPX + n0);
#pragma unroll
        for (int i = 0; i < 8; ++i) {
            const float wgt = __expf(mp[i] - M[i]);
            L[i] += wgt * lp[i];
            O[i] += wgt * bf2f((unsigned short)v8[i]);
        }
    }

    const float gm = gamma[0];
    const size_t xo = (size_t)bc * NPX + n0;
    float4 r0, r1;
    const float4 x0 = *(const float4*)(x + xo);
    const float4 x1 = *(const float4*)(x + xo + 4);
    r0.x = gm * O[0] / L[0] + x0.x;  r0.y = gm * O[1] / L[1] + x0.y;
    r0.z = gm * O[2] / L[2] + x0.z;  r0.w = gm * O[3] / L[3] + x0.w;
    r1.x = gm * O[4] / L[4] + x1.x;  r1.y = gm * O[5] / L[5] + x1.y;
    r1.z = gm * O[6] / L[6] + x1.z;  r1.w = gm * O[7] / L[7] + x1.w;
    *(float4*)(out + xo)     = r0;
    *(float4*)(out + xo + 4) = r1;
}

extern "C" void kernel_launch(void* const* d_in, const int* in_sizes, int n_in,
                              void* d_out, int out_size, void* d_ws, size_t ws_size,
                              hipStream_t stream)
{
    const float* x  = (const float*)d_in[0];
    const float* Wq = (const float*)d_in[1];
    const float* bq = (const float*)d_in[2];
    const float* Wk = (const float*)d_in[3];
    const float* bk = (const float*)d_in[4];
    const float* Wv = (const float*)d_in[5];
    const float* bv = (const float*)d_in[6];
    const float* gm = (const float*)d_in[7];
    float* out = (float*)d_out;
    unsigned short* ws = (unsigned short*)d_ws;

    const size_t qkvB   = (size_t)(2 * NB * NPX * 32 + NB * CCH * NPX) * 2;  // 10 MB
    const size_t partB  = (size_t)NB * CCH * NPX * 2;                        // 8 MB / slice
    const size_t mlB    = (size_t)2 * NB * NPX * 4;                          // 128 KB / slice
    int ns = 1;
    if      (ws_size >= qkvB + 4 * (partB + mlB)) ns = 4;
    else if (ws_size >= qkvB + 2 * (partB + mlB)) ns = 2;

    // proj: 64 pixel-slabs (NB*16) x 20 oc-groups, slab pinned to XCD
    proj_kernel<<<1280, 256, 0, stream>>>(x, Wq, bq, Wk, bk, Wv, bv, ws);

    const unsigned short* qT = ws;
    const unsigned short* kT = ws + (size_t)NB * NPX * 32;
    const unsigned short* vB = ws + (size_t)2 * NB * NPX * 32;

    // grid: NB batches x (NPX/BQ2) tiles x ns slices, one job per block
    const int ablocks = NB * (NPX / BQ2) * ns;

    if (ns > 1) {
        unsigned short* opart = ws + (size_t)2 * NB * NPX * 32 + (size_t)NB * CCH * NPX;
        float* mlm = (float*)(opart + (size_t)ns * NB * CCH * NPX);
        float* mll = mlm + (size_t)ns * NB * NPX;

        attn_kernel<<<ablocks, 512, 0, stream>>>(qT, kT, vB, x, gm, out,
                                                 opart, mlm, mll, ns);

        const int cblocks = (NB * CCH * (NPX / 8)) / 256;
        combine_kernel<<<cblocks, 256, 0, stream>>>(opart, mlm, mll, x, gm, out, ns);
    } else {
        attn_kernel<<<ablocks, 512, 0, stream>>>(qT, kT, vB, x, gm, out,
                                                 nullptr, nullptr, nullptr, 1);
    }
}

// Round 14
// 101.027 us; speedup vs baseline: 2.1815x; 2.1815x over previous
//
#include <hip/hip_runtime.h>
#include <cstddef>
#include <cstdint>

#define CCH 256   // channels
#define DQK 32    // q/k channels
#define NPX 4096  // H*W
#define BQ2 128   // queries per block (8 waves x 16-query strips)
#define BM  64    // key tile per iteration
#define NB  4     // batch

typedef __attribute__((ext_vector_type(8))) short bf16x8;   // 8 bf16 = 4 VGPR (MFMA A/B frag)
typedef __attribute__((ext_vector_type(4))) float f32x4;    // MFMA C/D frag
typedef __attribute__((ext_vector_type(4))) unsigned int u32x4;

__device__ inline unsigned short f2bf(float f) {            // RNE float->bf16
    unsigned u = __builtin_bit_cast(unsigned, f);
    u += 0x7FFFu + ((u >> 16) & 1u);
    return (unsigned short)(u >> 16);
}
__device__ inline float bf2f(unsigned short h) {
    unsigned u = (unsigned)h << 16;
    return __builtin_bit_cast(float, u);
}

// ---------------------------------------------------------------------------
// convert_kernel: pack W rows (Wq|Wk|Wv -> 320x256) to bf16 Wb, and the
// fused bias vector bb[320] (fp32). 320 blocks x 256 threads.
// ---------------------------------------------------------------------------
__global__ __launch_bounds__(256) void convert_kernel(
    const float* __restrict__ Wq, const float* __restrict__ bq,
    const float* __restrict__ Wk, const float* __restrict__ bk,
    const float* __restrict__ Wv, const float* __restrict__ bv,
    unsigned short* __restrict__ Wb, float* __restrict__ bb)
{
    const int o = blockIdx.x;
    const int c = threadIdx.x;
    float v;
    if (o < 32)       v = Wq[o * CCH + c];
    else if (o < 64)  v = Wk[(o - 32) * CCH + c];
    else              v = Wv[(o - 64) * CCH + c];
    Wb[o * CCH + c] = f2bf(v);
    if (c == 0)
        bb[o] = (o < 32) ? bq[o] : (o < 64) ? bk[o - 32] : bv[o - 64];
}

// ---------------------------------------------------------------------------
// proj_mfma: out[oc][px] = sum_c W[oc][c] x[c][px] + bias, bf16 MFMA.
// Block: one (batch, 64-px tile, 64-oc group). 512 thr / 8 waves.
// Stage: x tile [256c][64px] fp32 -> LDS xT[64px][264c pad] bf16 (transposed).
// Wave w: m-tile mt=w>>1 (16 oc), n-tiles (w&1)*2,(w&1)*2+1 (16 px each),
// K=256 in 8 MFMA steps. Same verified frag pattern as attn (A=[m][k],
// B=[n][k] 16B frags, D col=ln row=4g+rr). 5 oc-groups of one px-tile are
// XCD-pinned so the x tile is read from HBM once then L2-hit.
// Outputs: ocg==0 -> qT/kT [px][32]; ocg>0 -> v [c][px].
// ---------------------------------------------------------------------------
__global__ __launch_bounds__(512) void proj_mfma(
    const float* __restrict__ x,
    const unsigned short* __restrict__ Wb, const float* __restrict__ bb,
    unsigned short* __restrict__ ws)
{
    __shared__ __align__(16) unsigned short xT[64][264];   // 33 KB

    const int tid  = threadIdx.x;
    const int lane = tid & 63;
    const int w    = tid >> 6;
    const int ln   = lane & 15;
    const int g    = lane >> 4;
    const int bid  = blockIdx.x;

    // decode: 8 XCD x (32 slabs x 5 ocg); slab = (b, px-tile)
    const int xcd  = bid & 7;
    const int idx  = bid >> 3;           // 0..159
    const int slab = xcd + 8 * (idx / 5);  // 0..255
    const int ocg  = idx % 5;
    const int b    = slab >> 6;
    const int pxt  = slab & 63;
    const int pxg0 = pxt * 64;

    // ---- A-frags (issued early; independent of LDS): Wb[ocg*64+mt*16+ln][k]
    const int mt    = w >> 1;
    const int ocrow = ocg * 64 + mt * 16 + ln;
    bf16x8 a[8];
#pragma unroll
    for (int k8 = 0; k8 < 8; ++k8)
        a[k8] = *(const bf16x8*)(Wb + (size_t)ocrow * CCH + k8 * 32 + g * 8);

    // ---- stage x tile -> xT (transposed, bf16)
    {
        const int pxl = (tid & 15) * 4;
        const int c0  = (tid >> 4) * 8;
        float4 xv[8];
#pragma unroll
        for (int cc = 0; cc < 8; ++cc)
            xv[cc] = *(const float4*)(x + ((size_t)(b * CCH + c0 + cc)) * NPX + pxg0 + pxl);
#pragma unroll
        for (int j = 0; j < 4; ++j) {
            unsigned u[4];
#pragma unroll
            for (int h = 0; h < 4; ++h) {
                const float f0 = ((const float*)&xv[2 * h])[j];
                const float f1 = ((const float*)&xv[2 * h + 1])[j];
                u[h] = (unsigned)f2bf(f0) | ((unsigned)f2bf(f1) << 16);
            }
            // NOTE: pairs (xv[0],xv[1]) are channels c0+0,c0+1 ... contiguous
            *(u32x4*)&xT[pxl + j][c0] = (u32x4){u[0], u[1], u[2], u[3]};
        }
    }
    __syncthreads();

    // ---- compute: 2 n-tiles per wave, K=256
    const int nt0 = (w & 1) * 2;
    const float4 bb4 = *(const float4*)(bb + ocg * 64 + mt * 16 + g * 4);
    f32x4 acc0 = (f32x4){bb4.x, bb4.y, bb4.z, bb4.w};
    f32x4 acc1 = acc0;
#pragma unroll
    for (int k8 = 0; k8 < 8; ++k8) {
        const bf16x8 b0 = *(const bf16x8*)&xT[nt0 * 16 + ln][k8 * 32 + g * 8];
        const bf16x8 b1 = *(const bf16x8*)&xT[nt0 * 16 + 16 + ln][k8 * 32 + g * 8];
        acc0 = __builtin_amdgcn_mfma_f32_16x16x32_bf16(a[k8], b0, acc0, 0, 0, 0);
        acc1 = __builtin_amdgcn_mfma_f32_16x16x32_bf16(a[k8], b1, acc1, 0, 0, 0);
    }

    // ---- store: D col=ln (px), row=4g+rr (oc)
    unsigned short* qT = ws;
    unsigned short* kT = ws + (size_t)NB * NPX * 32;
    unsigned short* vb = ws + (size_t)2 * NB * NPX * 32;
#pragma unroll
    for (int j = 0; j < 2; ++j) {
        const f32x4 acc = j ? acc1 : acc0;
        const int px = pxg0 + (nt0 + j) * 16 + ln;
        if (ocg == 0) {
            const unsigned lo = (unsigned)f2bf(acc[0]) | ((unsigned)f2bf(acc[1]) << 16);
            const unsigned hi = (unsigned)f2bf(acc[2]) | ((unsigned)f2bf(acc[3]) << 16);
            unsigned short* dst = (mt < 2)
                ? qT + ((size_t)b * NPX + px) * 32 + mt * 16 + g * 4
                : kT + ((size_t)b * NPX + px) * 32 + (mt - 2) * 16 + g * 4;
            *(uint2*)dst = make_uint2(lo, hi);
        } else {
            const int c_row = (ocg - 1) * 64 + mt * 16 + g * 4;
#pragma unroll
            for (int rr = 0; rr < 4; ++rr)
                vb[((size_t)(b * CCH + c_row + rr)) * NPX + px] = f2bf(acc[rr]);
        }
    }
}

// ---------------------------------------------------------------------------
// Flash attention (exact R12 known-good: 71 us). BQ2=128 q/block, 8 waves,
// double-buffered P, ONE barrier/iter, defer-max rescale skip. ns slices.
// ---------------------------------------------------------------------------
__global__ __launch_bounds__(512, 4) void attn_kernel(
    const unsigned short* __restrict__ qT, const unsigned short* __restrict__ kT,
    const unsigned short* __restrict__ vB, const float* __restrict__ x,
    const float* __restrict__ gamma, float* __restrict__ out,
    unsigned short* __restrict__ opart, float* __restrict__ mlm,
    float* __restrict__ mll, int ns)
{
    __shared__ __align__(16) unsigned short Pl[2][BQ2 * 64];  // 32KB, XOR swz
    __shared__ float scb[2][BQ2];
    __shared__ int   flg[2][8];
    __shared__ float l_lds[BQ2];

    const int tid  = threadIdx.x;
    const int lane = tid & 63;
    const int w    = tid >> 6;       // wave 0..7
    const int ln   = lane & 15;
    const int g    = lane >> 4;      // 16-lane group 0..3
    const int bid  = blockIdx.x;

    const int b    = (bid & 7) >> 1;                        // batch -> XCD pair
    const int jb   = ((bid >> 3) << 1) | (bid & 1);         // job in batch
    const int tile = jb / ns;
    const int s    = jb - tile * ns;
    const int n0   = tile * BQ2;

    const bf16x8 qf = *(const bf16x8*)(qT + ((size_t)b * NPX + n0 + w * 16 + ln) * 32 + g * 8);

    f32x4 acc[8][2];
#pragma unroll
    for (int qt = 0; qt < 8; ++qt) {
        acc[qt][0] = (f32x4){0.f, 0.f, 0.f, 0.f};
        acc[qt][1] = (f32x4){0.f, 0.f, 0.f, 0.f};
    }
    float mreg = -INFINITY, lreg = 0.f;

    const unsigned short* kTb = kT + (size_t)b * NPX * 32;
    const unsigned short* vb  = vB + ((size_t)b * CCH + w * 32) * NPX;
    const int kbase = s * (NPX / ns);
    const int iters = NPX / (ns * BM);
    const unsigned swz   = ((unsigned)ln & 7u) << 4;
    const unsigned myrow = (unsigned)(w * 16 + ln) * 128u;

    for (int t = 0; t < iters; ++t) {
        const int m0 = kbase + t * BM;

        f32x4 e[4];
#pragma unroll
        for (int s4 = 0; s4 < 4; ++s4) {
            const bf16x8 ka = *(const bf16x8*)(kTb + (size_t)(m0 + s4 * 16 + ln) * 32 + g * 8);
            e[s4] = __builtin_amdgcn_mfma_f32_16x16x32_bf16(
                        ka, qf, (f32x4){0.f, 0.f, 0.f, 0.f}, 0, 0, 0);
        }

        float lm = -INFINITY;
#pragma unroll
        for (int s4 = 0; s4 < 4; ++s4)
#pragma unroll
            for (int rr = 0; rr < 4; ++rr) lm = fmaxf(lm, e[s4][rr]);
        lm = fmaxf(lm, __shfl_xor(lm, 16));
        lm = fmaxf(lm, __shfl_xor(lm, 32));
        const float mnew = (lm <= mreg + 8.0f) ? mreg : lm;
        const float sc   = __expf(mreg - mnew);
        float ps = 0.f;
#pragma unroll
        for (int s4 = 0; s4 < 4; ++s4)
#pragma unroll
            for (int rr = 0; rr < 4; ++rr) {
                const float p = __expf(e[s4][rr] - mnew);
                e[s4][rr] = p;
                ps += p;
            }
        ps += __shfl_xor(ps, 16);
        ps += __shfl_xor(ps, 32);
        lreg = lreg * sc + ps;
        mreg = mnew;

        const int bw = t & 1;
        char* const pwb = (char*)&Pl[bw][0];
#pragma unroll
        for (int s4 = 0; s4 < 4; ++s4) {
            uint2 pk;
            pk.x = (unsigned)f2bf(e[s4][0]) | ((unsigned)f2bf(e[s4][1]) << 16);
            pk.y = (unsigned)f2bf(e[s4][2]) | ((unsigned)f2bf(e[s4][3]) << 16);
            *(uint2*)(pwb + myrow + (((unsigned)(s4 * 32 + g * 8)) ^ swz)) = pk;
        }
        if (g == 0) scb[bw][w * 16 + ln] = sc;
        const int allsk = __all(sc == 1.0f);
        if (lane == 0) flg[bw][w] = allsk;
        __syncthreads();   // the ONLY barrier per iteration

        int sk = flg[bw][0];
#pragma unroll
        for (int i = 1; i < 8; ++i) sk &= flg[bw][i];
        if (!sk) {
#pragma unroll
            for (int qt = 0; qt < 8; ++qt) {
                const float scq = scb[bw][qt * 16 + ln];
#pragma unroll
                for (int rr = 0; rr < 4; ++rr) {
                    acc[qt][0][rr] *= scq;
                    acc[qt][1][rr] *= scq;
                }
            }
        }
        bf16x8 va[2][2];
#pragma unroll
        for (int ct = 0; ct < 2; ++ct) {
            const unsigned short* vrow = vb + (size_t)(ct * 16 + ln) * NPX + m0 + g * 8;
            va[ct][0] = *(const bf16x8*)(vrow);
            va[ct][1] = *(const bf16x8*)(vrow + 32);
        }
#pragma unroll
        for (int qt = 0; qt < 8; ++qt) {
            const unsigned rb = (unsigned)(qt * 16 + ln) * 128u;
            const bf16x8 pf0 = *(const bf16x8*)(pwb + rb + (((unsigned)(g * 16))      ^ swz));
            const bf16x8 pf1 = *(const bf16x8*)(pwb + rb + (((unsigned)(64 + g * 16)) ^ swz));
            acc[qt][0] = __builtin_amdgcn_mfma_f32_16x16x32_bf16(va[0][0], pf0, acc[qt][0], 0, 0, 0);
            acc[qt][0] = __builtin_amdgcn_mfma_f32_16x16x32_bf16(va[0][1], pf1, acc[qt][0], 0, 0, 0);
            acc[qt][1] = __builtin_amdgcn_mfma_f32_16x16x32_bf16(va[1][0], pf0, acc[qt][1], 0, 0, 0);
            acc[qt][1] = __builtin_amdgcn_mfma_f32_16x16x32_bf16(va[1][1], pf1, acc[qt][1], 0, 0, 0);
        }
    }

    if (opart) {
        const size_t sb = (size_t)(s * NB + b);
#pragma unroll
        for (int qt = 0; qt < 8; ++qt)
#pragma unroll
            for (int ct = 0; ct < 2; ++ct) {
                const size_t c0 = sb * CCH + w * 32 + ct * 16 + g * 4;
#pragma unroll
                for (int rr = 0; rr < 4; ++rr)
                    opart[(c0 + rr) * NPX + n0 + qt * 16 + ln] = f2bf(acc[qt][ct][rr]);
            }
        if (g == 0) {
            mlm[sb * NPX + n0 + w * 16 + ln] = mreg;
            mll[sb * NPX + n0 + w * 16 + ln] = lreg;
        }
    } else {
        if (g == 0) l_lds[w * 16 + ln] = lreg;
        __syncthreads();
        const float gm = gamma[0];
#pragma unroll
        for (int qt = 0; qt < 8; ++qt) {
            const float iv = 1.f / l_lds[qt * 16 + ln];
#pragma unroll
            for (int ct = 0; ct < 2; ++ct) {
                const size_t c0 = (size_t)b * CCH + w * 32 + ct * 16 + g * 4;
#pragma unroll
                for (int rr = 0; rr < 4; ++rr) {
                    const size_t idx = (c0 + rr) * NPX + n0 + qt * 16 + ln;
                    out[idx] = gm * acc[qt][ct][rr] * iv + x[idx];
                }
            }
        }
    }
}

// ---------------------------------------------------------------------------
// Combine: log-sum-exp merge of ns key-slice partials + gamma/residual.
// ---------------------------------------------------------------------------
__global__ __launch_bounds__(256) void combine_kernel(
    const unsigned short* __restrict__ opart,
    const float* __restrict__ mlm, const float* __restrict__ mll,
    const float* __restrict__ x, const float* __restrict__ gamma,
    float* __restrict__ out, int ns)
{
    const int idx = blockIdx.x * 256 + threadIdx.x;   // NB*CCH*512 threads
    const int bc  = idx >> 9;                          // b*CCH + c
    const int b   = bc / CCH;
    const int c   = bc - b * CCH;
    const int n0  = (idx & 511) * 8;

    float M[8];
#pragma unroll
    for (int i = 0; i < 8; ++i) M[i] = -INFINITY;
    for (int s = 0; s < ns; ++s) {
        const float* mp = mlm + ((size_t)(s * NB + b)) * NPX + n0;
#pragma unroll
        for (int i = 0; i < 8; ++i) M[i] = fmaxf(M[i], mp[i]);
    }

    float L[8], O[8];
#pragma unroll
    for (int i = 0; i < 8; ++i) { L[i] = 0.f; O[i] = 0.f; }
    for (int s = 0; s < ns; ++s) {
        const size_t sb = (size_t)(s * NB + b);
        const float* mp = mlm + sb * NPX + n0;
        const float* lp = mll + sb * NPX + n0;
        const bf16x8 v8 = *(const bf16x8*)(opart + (sb * CCH + c) * NPX + n0);
#pragma unroll
        for (int i = 0; i < 8; ++i) {
            const float wgt = __expf(mp[i] - M[i]);
            L[i] += wgt * lp[i];
            O[i] += wgt * bf2f((unsigned short)v8[i]);
        }
    }

    const float gm = gamma[0];
    const size_t xo = (size_t)bc * NPX + n0;
    float4 r0, r1;
    const float4 x0 = *(const float4*)(x + xo);
    const float4 x1 = *(const float4*)(x + xo + 4);
    r0.x = gm * O[0] / L[0] + x0.x;  r0.y = gm * O[1] / L[1] + x0.y;
    r0.z = gm * O[2] / L[2] + x0.z;  r0.w = gm * O[3] / L[3] + x0.w;
    r1.x = gm * O[4] / L[4] + x1.x;  r1.y = gm * O[5] / L[5] + x1.y;
    r1.z = gm * O[6] / L[6] + x1.z;  r1.w = gm * O[7] / L[7] + x1.w;
    *(float4*)(out + xo)     = r0;
    *(float4*)(out + xo + 4) = r1;
}

extern "C" void kernel_launch(void* const* d_in, const int* in_sizes, int n_in,
                              void* d_out, int out_size, void* d_ws, size_t ws_size,
                              hipStream_t stream)
{
    const float* x  = (const float*)d_in[0];
    const float* Wq = (const float*)d_in[1];
    const float* bq = (const float*)d_in[2];
    const float* Wk = (const float*)d_in[3];
    const float* bk = (const float*)d_in[4];
    const float* Wv = (const float*)d_in[5];
    const float* bv = (const float*)d_in[6];
    const float* gm = (const float*)d_in[7];
    float* out = (float*)d_out;
    unsigned short* ws = (unsigned short*)d_ws;

    const size_t WB_U16 = 320 * CCH;          // 81920
    const size_t BB_U16 = 320 * 2;            // 320 floats
    const size_t qkvU   = (size_t)2 * NB * NPX * 32 + (size_t)NB * CCH * NPX;
    const size_t qkvB   = (qkvU + WB_U16 + BB_U16) * 2;
    const size_t partB  = (size_t)NB * CCH * NPX * 2;                        // 8 MB / slice
    const size_t mlB    = (size_t)2 * NB * NPX * 4;                          // 128 KB / slice
    int ns = 1;
    if      (ws_size >= qkvB + 4 * (partB + mlB)) ns = 4;
    else if (ws_size >= qkvB + 2 * (partB + mlB)) ns = 2;

    unsigned short* Wb = ws + qkvU;
    float*          bb = (float*)(ws + qkvU + WB_U16);

    convert_kernel<<<320, 256, 0, stream>>>(Wq, bq, Wk, bk, Wv, bv, Wb, bb);

    // proj: 8 XCD x (32 slabs x 5 ocg) = 1280 blocks, 512 thr
    proj_mfma<<<1280, 512, 0, stream>>>(x, Wb, bb, ws);

    const unsigned short* qT = ws;
    const unsigned short* kT = ws + (size_t)NB * NPX * 32;
    const unsigned short* vB = ws + (size_t)2 * NB * NPX * 32;

    const int ablocks = NB * (NPX / BQ2) * ns;

    if (ns > 1) {
        unsigned short* opart = ws + qkvU + WB_U16 + BB_U16;
        float* mlm = (float*)(opart + (size_t)ns * NB * CCH * NPX);
        float* mll = mlm + (size_t)ns * NB * NPX;

        attn_kernel<<<ablocks, 512, 0, stream>>>(qT, kT, vB, x, gm, out,
                                                 opart, mlm, mll, ns);

        const int cblocks = (NB * CCH * (NPX / 8)) / 256;
        combine_kernel<<<cblocks, 256, 0, stream>>>(opart, mlm, mll, x, gm, out, ns);
    } else {
        attn_kernel<<<ablocks, 512, 0, stream>>>(qT, kT, vB, x, gm, out,
                                                 nullptr, nullptr, nullptr, 1);
    }
}